// Round 6
// baseline (130.308 us; speedup 1.0000x reference)
//
#include <hip/hip_runtime.h>

#define P_SZ 1152
#define DP 8
#define DS 16
#define NTHR 768
#define NQ 192           // thread-quads per block; quad pq owns p = r*NQ + pq
#define PT 6             // p's per thread per b
#define NW 12            // waves per block
#define XQ 2304          // float4s of x per b (1152 p * 2 float4)

// Persistent-register budget is the whole game on this kernel: the allocator
// gives ~64 arch VGPRs and shunts the rest to AGPRs (v_accvgpr moves) or
// scratch. Quad layout at 768 threads -> PT=6 -> persistent state =
// uh 48 + vacc 8 + sv 8 = 64 floats: fits the arch file.
// vacc trick: b_logits never materialized; bl_it[p] = (sum_{tau<it} v_tau).uh[p]
// recomputed in the softmax pass (this IS the agreement pass, merged).
// x staged in LDS (73.7 KB) so build transients are just W (8 regs) + addr.
// launch_bounds(768,6): cap ~85 regs -> 2 blocks/CU = 24 waves (75% occ);
// LDS 77 KB * 2 = 154 KB <= 160 KB.
__global__ __launch_bounds__(NTHR, 6)
void caps_routing8(const float* __restrict__ x, const float* __restrict__ W,
                   float* __restrict__ out) {
    __shared__ float4 xs[2 * XQ];         // 73.7 KB
    __shared__ float red[2][NW][2][17];   // 3.3 KB [buf][wave][b][j=0..15,16=esum]

    const int t    = threadIdx.x;
    const int lane = t & 63;
    const int jq   = t & 3;
    const int pq   = t >> 2;
    const int w    = t >> 6;
    const int bid  = blockIdx.x;
    const int s    = bid & 31;            // same-s blocks share one XCD L2
    const int b0   = (bid >> 5) << 1;

    float uh0[PT][4], uh1[PT][4];

    // ---- stage x for both b's (contiguous rows) into LDS ----
    {
        const float4* xg = (const float4*)(x + (size_t)b0 * (P_SZ * DP));
        #pragma unroll
        for (int k = 0; k < 6; ++k) {     // 2*XQ = 4608 = 6*768
            const int idx = t + k * NTHR;
            xs[idx] = xg[idx];
        }
    }
    __syncthreads();

    // ---- build u_hat: per quad, 4 jq lanes cover one p's 512 B of W ----
    #pragma unroll
    for (int r = 0; r < PT; ++r) {
        const int p = r * NQ + pq;
        const float* wp = W + (size_t)(s * P_SZ + p) * (DS * DP) + jq * DP;
        const float4 xa0 = xs[2*p],      xa1 = xs[2*p + 1];        // b0
        const float4 xc0 = xs[XQ + 2*p], xc1 = xs[XQ + 2*p + 1];   // b0+1
        #pragma unroll
        for (int jj = 0; jj < 4; ++jj) {   // j = jq + 4*jj
            const float4 w0 = *(const float4*)(wp + jj * 32);
            const float4 w1 = *(const float4*)(wp + jj * 32 + 4);
            uh0[r][jj] = w0.x*xa0.x + w0.y*xa0.y + w0.z*xa0.z + w0.w*xa0.w
                       + w1.x*xa1.x + w1.y*xa1.y + w1.z*xa1.z + w1.w*xa1.w;
            uh1[r][jj] = w0.x*xc0.x + w0.y*xc0.y + w0.z*xc0.z + w0.w*xc0.w
                       + w1.x*xc1.x + w1.y*xc1.y + w1.z*xc1.z + w1.w*xc1.w;
        }
    }

    // ---------------- iteration 0: c = 1/P ----------------
    float sv0[4], sv1[4];
    #pragma unroll
    for (int jj = 0; jj < 4; ++jj) {
        float a = 0.f, c = 0.f;
        #pragma unroll
        for (int r = 0; r < PT; ++r) { a += uh0[r][jj]; c += uh1[r][jj]; }
        sv0[jj] = a; sv1[jj] = c;
    }
    #pragma unroll
    for (int off = 4; off < 64; off <<= 1) {
        #pragma unroll
        for (int jj = 0; jj < 4; ++jj) {
            sv0[jj] += __shfl_xor(sv0[jj], off);
            sv1[jj] += __shfl_xor(sv1[jj], off);
        }
    }
    if (lane < 4) {
        #pragma unroll
        for (int jj = 0; jj < 4; ++jj) {
            red[0][w][0][jq + 4*jj] = sv0[jj];
            red[0][w][1][jq + 4*jj] = sv1[jj];
        }
    }
    __syncthreads();
    #pragma unroll
    for (int jj = 0; jj < 4; ++jj) { sv0[jj] = 0.f; sv1[jj] = 0.f; }
    #pragma unroll
    for (int ww = 0; ww < NW; ++ww) {
        #pragma unroll
        for (int jj = 0; jj < 4; ++jj) {
            sv0[jj] += red[0][ww][0][jq + 4*jj];   // same-address broadcast reads
            sv1[jj] += red[0][ww][1][jq + 4*jj];
        }
    }
    #pragma unroll
    for (int jj = 0; jj < 4; ++jj) { sv0[jj] *= (1.f / P_SZ); sv1[jj] *= (1.f / P_SZ); }

    float sq0 = sv0[0]*sv0[0] + sv0[1]*sv0[1] + sv0[2]*sv0[2] + sv0[3]*sv0[3];
    float sq1 = sv1[0]*sv1[0] + sv1[1]*sv1[1] + sv1[2]*sv1[2] + sv1[3]*sv1[3];
    sq0 += __shfl_xor(sq0, 1); sq0 += __shfl_xor(sq0, 2);
    sq1 += __shfl_xor(sq1, 1); sq1 += __shfl_xor(sq1, 2);
    float f0 = sq0 / (1.f + sq0) / (sqrtf(sq0) + 1e-7f);
    float f1 = sq1 / (1.f + sq1) / (sqrtf(sq1) + 1e-7f);
    // vacc = accumulated v across iterations (replaces b_logits entirely)
    float va0[4], va1[4];
    #pragma unroll
    for (int jj = 0; jj < 4; ++jj) { va0[jj] = f0 * sv0[jj]; va1[jj] = f1 * sv1[jj]; }

    // ---------------- iterations 1, 2 ----------------
    #pragma unroll
    for (int it = 1; it < 3; ++it) {
        float es0 = 0.f, es1 = 0.f;
        #pragma unroll
        for (int jj = 0; jj < 4; ++jj) { sv0[jj] = 0.f; sv1[jj] = 0.f; }
        // fused: logit (= vacc . uh, quad-reduced) -> exp -> softmax num+denom
        #pragma unroll
        for (int r = 0; r < PT; ++r) {
            float d0 = va0[0]*uh0[r][0] + va0[1]*uh0[r][1]
                     + va0[2]*uh0[r][2] + va0[3]*uh0[r][3];
            float d1 = va1[0]*uh1[r][0] + va1[1]*uh1[r][1]
                     + va1[2]*uh1[r][2] + va1[3]*uh1[r][3];
            d0 += __shfl_xor(d0, 1); d0 += __shfl_xor(d0, 2);
            d1 += __shfl_xor(d1, 1); d1 += __shfl_xor(d1, 2);
            const float e0 = __expf(d0);
            const float e1 = __expf(d1);
            es0 += e0; es1 += e1;
            #pragma unroll
            for (int jj = 0; jj < 4; ++jj) {
                sv0[jj] += e0 * uh0[r][jj];
                sv1[jj] += e1 * uh1[r][jj];
            }
        }
        #pragma unroll
        for (int off = 4; off < 64; off <<= 1) {   // joint 10-value wave reduce
            es0 += __shfl_xor(es0, off);
            es1 += __shfl_xor(es1, off);
            #pragma unroll
            for (int jj = 0; jj < 4; ++jj) {
                sv0[jj] += __shfl_xor(sv0[jj], off);
                sv1[jj] += __shfl_xor(sv1[jj], off);
            }
        }
        const int buf = it & 1;
        if (lane < 4) {
            #pragma unroll
            for (int jj = 0; jj < 4; ++jj) {
                red[buf][w][0][jq + 4*jj] = sv0[jj];
                red[buf][w][1][jq + 4*jj] = sv1[jj];
            }
            if (lane == 0) { red[buf][w][0][16] = es0; red[buf][w][1][16] = es1; }
        }
        __syncthreads();
        es0 = 0.f; es1 = 0.f;
        #pragma unroll
        for (int jj = 0; jj < 4; ++jj) { sv0[jj] = 0.f; sv1[jj] = 0.f; }
        #pragma unroll
        for (int ww = 0; ww < NW; ++ww) {
            es0 += red[buf][ww][0][16];
            es1 += red[buf][ww][1][16];
            #pragma unroll
            for (int jj = 0; jj < 4; ++jj) {
                sv0[jj] += red[buf][ww][0][jq + 4*jj];
                sv1[jj] += red[buf][ww][1][jq + 4*jj];
            }
        }
        const float r0 = 1.f / es0, r1 = 1.f / es1;
        #pragma unroll
        for (int jj = 0; jj < 4; ++jj) { sv0[jj] *= r0; sv1[jj] *= r1; }

        sq0 = sv0[0]*sv0[0] + sv0[1]*sv0[1] + sv0[2]*sv0[2] + sv0[3]*sv0[3];
        sq1 = sv1[0]*sv1[0] + sv1[1]*sv1[1] + sv1[2]*sv1[2] + sv1[3]*sv1[3];
        sq0 += __shfl_xor(sq0, 1); sq0 += __shfl_xor(sq0, 2);
        sq1 += __shfl_xor(sq1, 1); sq1 += __shfl_xor(sq1, 2);
        f0 = sq0 / (1.f + sq0) / (sqrtf(sq0) + 1e-7f);
        f1 = sq1 / (1.f + sq1) / (sqrtf(sq1) + 1e-7f);

        if (it == 2) {
            if (t < 4) {
                #pragma unroll
                for (int jj = 0; jj < 4; ++jj)
                    out[(size_t)(b0 * 32 + s) * DS + jq + 4*jj] = f0 * sv0[jj];
            } else if (t < 8) {
                #pragma unroll
                for (int jj = 0; jj < 4; ++jj)
                    out[(size_t)((b0 + 1) * 32 + s) * DS + jq + 4*jj] = f1 * sv1[jj];
            }
        } else {
            #pragma unroll
            for (int jj = 0; jj < 4; ++jj) {
                va0[jj] += f0 * sv0[jj];
                va1[jj] += f1 * sv1[jj];
            }
        }
    }
}

extern "C" void kernel_launch(void* const* d_in, const int* in_sizes, int n_in,
                              void* d_out, int out_size, void* d_ws, size_t ws_size,
                              hipStream_t stream) {
    const float* x = (const float*)d_in[0];   // (128, 1152, 8) fp32
    const float* W = (const float*)d_in[1];   // (32, 1152, 16, 8) fp32
    float* out = (float*)d_out;               // (128, 32, 16) fp32
    caps_routing8<<<dim3(32 * 64), dim3(NTHR), 0, stream>>>(x, W, out);
}

// Round 7
// 75.095 us; speedup vs baseline: 1.7352x; 1.7352x over previous
//
#include <hip/hip_runtime.h>

#define P_SZ 1152
#define DP 8
#define DS 16
#define NTHR 512
#define NQ 128           // thread-quads per block; quad pq owns p = r*NQ + pq
#define PT 9             // p's per thread per b
#define NW 8             // waves per block

// R3 champion structure, unchanged:
//   thread (pq = t>>2, jq = t&3) owns u_hat[b][p = r*128+pq][j = jq+4*jj],
//   72 uh regs; b_logits never materialized (vacc trick:
//   bl_it[p] = (sum_{tau<it} v_tau) . uh[p], recomputed in the softmax pass);
//   quad xor1/2 for j-dots, xor4..32 + one 8-wave LDS round for p-sums.
// Single change vs R3: sched_barrier(0) between build r-iterations. The
// fully-unrolled build (required: uh[r][jj] must have static indices) lets
// the scheduler hoist ~3 iterations of W/x dwordx4 loads -> ~140 transient
// regs on top of uh's live range -> ~7 floats of scratch (29 MB HBM writes
// in R3). The barrier caps in-flight loads at one iteration (48 regs),
// peak ~120 < 128 cap -> zero scratch. Latency hidden by 4 waves/SIMD TLP.
__global__ __launch_bounds__(NTHR, 4)
void caps_routing9(const float* __restrict__ x, const float* __restrict__ W,
                   float* __restrict__ out) {
    __shared__ float red[2][NW][2][17];   // [buf][wave][b][j=0..15, 16=esum]

    const int t    = threadIdx.x;
    const int lane = t & 63;
    const int jq   = t & 3;
    const int pq   = t >> 2;
    const int w    = t >> 6;
    const int bid  = blockIdx.x;
    const int s    = bid & 31;            // same-s blocks share one XCD L2
    const int b0   = (bid >> 5) << 1;

    float uh0[PT][4], uh1[PT][4];

    const float* xb0 = x + (size_t)b0 * (P_SZ * DP);
    const float* xb1 = xb0 + P_SZ * DP;

    // ---- build u_hat: per quad, 4 jq lanes cover one p's 512 B of W ----
    #pragma unroll
    for (int r = 0; r < PT; ++r) {
        const int p = (r << 7) + pq;
        const float* wp = W + (size_t)(s * P_SZ + p) * (DS * DP) + jq * DP;
        const float4 xa0 = *(const float4*)(xb0 + p * DP);
        const float4 xa1 = *(const float4*)(xb0 + p * DP + 4);
        const float4 xc0 = *(const float4*)(xb1 + p * DP);
        const float4 xc1 = *(const float4*)(xb1 + p * DP + 4);
        #pragma unroll
        for (int jj = 0; jj < 4; ++jj) {   // j = jq + 4*jj
            const float4 w0 = *(const float4*)(wp + jj * 32);
            const float4 w1 = *(const float4*)(wp + jj * 32 + 4);
            uh0[r][jj] = w0.x*xa0.x + w0.y*xa0.y + w0.z*xa0.z + w0.w*xa0.w
                       + w1.x*xa1.x + w1.y*xa1.y + w1.z*xa1.z + w1.w*xa1.w;
            uh1[r][jj] = w0.x*xc0.x + w0.y*xc0.y + w0.z*xc0.z + w0.w*xc0.w
                       + w1.x*xc1.x + w1.y*xc1.y + w1.z*xc1.z + w1.w*xc1.w;
        }
        __builtin_amdgcn_sched_barrier(0);   // cap in-flight loads at 1 iter
    }

    // ---------------- iteration 0: c = 1/P ----------------
    float sv0[4], sv1[4];
    #pragma unroll
    for (int jj = 0; jj < 4; ++jj) {
        float a = 0.f, c = 0.f;
        #pragma unroll
        for (int r = 0; r < PT; ++r) { a += uh0[r][jj]; c += uh1[r][jj]; }
        sv0[jj] = a; sv1[jj] = c;
    }
    #pragma unroll
    for (int off = 4; off < 64; off <<= 1) {
        #pragma unroll
        for (int jj = 0; jj < 4; ++jj) {
            sv0[jj] += __shfl_xor(sv0[jj], off);
            sv1[jj] += __shfl_xor(sv1[jj], off);
        }
    }
    if (lane < 4) {
        #pragma unroll
        for (int jj = 0; jj < 4; ++jj) {
            red[0][w][0][jq + 4*jj] = sv0[jj];
            red[0][w][1][jq + 4*jj] = sv1[jj];
        }
    }
    __syncthreads();
    #pragma unroll
    for (int jj = 0; jj < 4; ++jj) { sv0[jj] = 0.f; sv1[jj] = 0.f; }
    #pragma unroll
    for (int ww = 0; ww < NW; ++ww) {
        #pragma unroll
        for (int jj = 0; jj < 4; ++jj) {
            sv0[jj] += red[0][ww][0][jq + 4*jj];   // same-address broadcast reads
            sv1[jj] += red[0][ww][1][jq + 4*jj];
        }
    }
    #pragma unroll
    for (int jj = 0; jj < 4; ++jj) { sv0[jj] *= (1.f / P_SZ); sv1[jj] *= (1.f / P_SZ); }

    float sq0 = sv0[0]*sv0[0] + sv0[1]*sv0[1] + sv0[2]*sv0[2] + sv0[3]*sv0[3];
    float sq1 = sv1[0]*sv1[0] + sv1[1]*sv1[1] + sv1[2]*sv1[2] + sv1[3]*sv1[3];
    sq0 += __shfl_xor(sq0, 1); sq0 += __shfl_xor(sq0, 2);
    sq1 += __shfl_xor(sq1, 1); sq1 += __shfl_xor(sq1, 2);
    float f0 = sq0 / (1.f + sq0) / (sqrtf(sq0) + 1e-7f);
    float f1 = sq1 / (1.f + sq1) / (sqrtf(sq1) + 1e-7f);
    // vacc = accumulated v across iterations (replaces b_logits entirely)
    float va0[4], va1[4];
    #pragma unroll
    for (int jj = 0; jj < 4; ++jj) { va0[jj] = f0 * sv0[jj]; va1[jj] = f1 * sv1[jj]; }

    // ---------------- iterations 1, 2 ----------------
    #pragma unroll
    for (int it = 1; it < 3; ++it) {
        float es0 = 0.f, es1 = 0.f;
        #pragma unroll
        for (int jj = 0; jj < 4; ++jj) { sv0[jj] = 0.f; sv1[jj] = 0.f; }
        // fused: logit (= vacc . uh, quad-reduced) -> exp -> softmax num+denom
        #pragma unroll
        for (int r = 0; r < PT; ++r) {
            float d0 = va0[0]*uh0[r][0] + va0[1]*uh0[r][1]
                     + va0[2]*uh0[r][2] + va0[3]*uh0[r][3];
            float d1 = va1[0]*uh1[r][0] + va1[1]*uh1[r][1]
                     + va1[2]*uh1[r][2] + va1[3]*uh1[r][3];
            d0 += __shfl_xor(d0, 1); d0 += __shfl_xor(d0, 2);
            d1 += __shfl_xor(d1, 1); d1 += __shfl_xor(d1, 2);
            const float e0 = __expf(d0);
            const float e1 = __expf(d1);
            es0 += e0; es1 += e1;
            #pragma unroll
            for (int jj = 0; jj < 4; ++jj) {
                sv0[jj] += e0 * uh0[r][jj];
                sv1[jj] += e1 * uh1[r][jj];
            }
        }
        #pragma unroll
        for (int off = 4; off < 64; off <<= 1) {   // joint 10-value wave reduce
            es0 += __shfl_xor(es0, off);
            es1 += __shfl_xor(es1, off);
            #pragma unroll
            for (int jj = 0; jj < 4; ++jj) {
                sv0[jj] += __shfl_xor(sv0[jj], off);
                sv1[jj] += __shfl_xor(sv1[jj], off);
            }
        }
        const int buf = it & 1;
        if (lane < 4) {
            #pragma unroll
            for (int jj = 0; jj < 4; ++jj) {
                red[buf][w][0][jq + 4*jj] = sv0[jj];
                red[buf][w][1][jq + 4*jj] = sv1[jj];
            }
            if (lane == 0) { red[buf][w][0][16] = es0; red[buf][w][1][16] = es1; }
        }
        __syncthreads();
        es0 = 0.f; es1 = 0.f;
        #pragma unroll
        for (int jj = 0; jj < 4; ++jj) { sv0[jj] = 0.f; sv1[jj] = 0.f; }
        #pragma unroll
        for (int ww = 0; ww < NW; ++ww) {
            es0 += red[buf][ww][0][16];
            es1 += red[buf][ww][1][16];
            #pragma unroll
            for (int jj = 0; jj < 4; ++jj) {
                sv0[jj] += red[buf][ww][0][jq + 4*jj];
                sv1[jj] += red[buf][ww][1][jq + 4*jj];
            }
        }
        const float r0 = 1.f / es0, r1 = 1.f / es1;
        #pragma unroll
        for (int jj = 0; jj < 4; ++jj) { sv0[jj] *= r0; sv1[jj] *= r1; }

        sq0 = sv0[0]*sv0[0] + sv0[1]*sv0[1] + sv0[2]*sv0[2] + sv0[3]*sv0[3];
        sq1 = sv1[0]*sv1[0] + sv1[1]*sv1[1] + sv1[2]*sv1[2] + sv1[3]*sv1[3];
        sq0 += __shfl_xor(sq0, 1); sq0 += __shfl_xor(sq0, 2);
        sq1 += __shfl_xor(sq1, 1); sq1 += __shfl_xor(sq1, 2);
        f0 = sq0 / (1.f + sq0) / (sqrtf(sq0) + 1e-7f);
        f1 = sq1 / (1.f + sq1) / (sqrtf(sq1) + 1e-7f);

        if (it == 2) {
            if (t < 4) {
                #pragma unroll
                for (int jj = 0; jj < 4; ++jj)
                    out[(size_t)(b0 * 32 + s) * DS + jq + 4*jj] = f0 * sv0[jj];
            } else if (t < 8) {
                #pragma unroll
                for (int jj = 0; jj < 4; ++jj)
                    out[(size_t)((b0 + 1) * 32 + s) * DS + jq + 4*jj] = f1 * sv1[jj];
            }
        } else {
            #pragma unroll
            for (int jj = 0; jj < 4; ++jj) {
                va0[jj] += f0 * sv0[jj];
                va1[jj] += f1 * sv1[jj];
            }
        }
    }
}

extern "C" void kernel_launch(void* const* d_in, const int* in_sizes, int n_in,
                              void* d_out, int out_size, void* d_ws, size_t ws_size,
                              hipStream_t stream) {
    const float* x = (const float*)d_in[0];   // (128, 1152, 8) fp32
    const float* W = (const float*)d_in[1];   // (32, 1152, 16, 8) fp32
    float* out = (float*)d_out;               // (128, 32, 16) fp32
    caps_routing9<<<dim3(32 * 64), dim3(NTHR), 0, stream>>>(x, W, out);
}